// Round 12
// baseline (149.178 us; speedup 1.0000x reference)
//
#include <hip/hip_runtime.h>
#include <math.h>

#define BB 8
#define TT 8192
#define XX 64
#define HH 128
#define CHUNK 32
#define NC (TT/CHUNK)

typedef __attribute__((ext_vector_type(8))) short short8;
typedef __attribute__((ext_vector_type(4))) float f32x4;

// fast sigmoid: v_rcp_f32 (~1 ulp) instead of IEEE div sequence. Used only in
// gru_mm, where ab/summaries/replay all consume the same values -> consistent.
__device__ __forceinline__ float sigm(float x){
  return __builtin_amdgcn_rcpf(1.0f + __expf(-x));
}
__device__ __forceinline__ unsigned short f2bf(float f){
  unsigned u = __float_as_uint(f);
  return (unsigned short)((u + 0x7fffu + ((u>>16)&1u)) >> 16);
}
__device__ __forceinline__ float bf2f(unsigned b){ return __uint_as_float(b << 16); }

// P0: build bf16 weight tables, pre-swizzled (byte ^= (col&7)<<4) so MFMA kernels
// stage LDS linearly and read with the same XOR -> conflict-free ds_read_b128.
__global__ __launch_bounds__(256) void prep_kernel(
    const float* __restrict__ w1, const float* __restrict__ w2, const float* __restrict__ w3,
    const float* __restrict__ ew, const float* __restrict__ pw,
    unsigned short* __restrict__ wt, unsigned short* __restrict__ wt_e, unsigned short* __restrict__ wt_p)
{
  int idx = blockIdx.x*256 + threadIdx.x;
  if (idx < 98304) {
    int l = idx >> 15;
    int e = idx & 32767;
    int k = e >> 8;
    int col = e & 255;
    const float* w = (l==0) ? w1 : ((l==1) ? w2 : w3);
    float v = w[e];
    unsigned byte = ((unsigned)col*128u + (unsigned)k)*2u;
    byte ^= (unsigned)((col & 7) << 4);
    wt[(size_t)l*32768 + (byte >> 1)] = f2bf(v);
  } else if (idx < 106496) {
    int e = idx - 98304;
    int col = e >> 6, k = e & 63;
    float v = ew[k*HH + col];
    unsigned byte = ((unsigned)e*2u) ^ (unsigned)((col & 7) << 4);
    wt_e[byte >> 1] = f2bf(v);
  } else if (idx < 114688) {
    int e = idx - 106496;
    int col = e >> 7, k = e & 127;
    float v = (col < 50) ? pw[k*50 + col] : 0.f;
    unsigned byte = ((unsigned)e*2u) ^ (unsigned)((col & 7) << 4);
    wt_p[byte >> 1] = f2bf(v);
  }
}

// K1: embed (64->128) MFMA + leaky_relu + LN0 -> h (bf16)   [round-5 green text]
__global__ __launch_bounds__(256) void embed_mfma_kernel(
    const float* __restrict__ x, const unsigned short* __restrict__ wt_e,
    const float* __restrict__ eb, const float* __restrict__ g, const float* __restrict__ be,
    unsigned short* __restrict__ hout)
{
  __shared__ short8 wlds[1024];
  int tid = threadIdx.x;
  const short8* wsrc = (const short8*)wt_e;
  #pragma unroll
  for (int i = 0; i < 4; ++i) wlds[i*256 + tid] = wsrc[i*256 + tid];

  int wid = tid >> 6, lane = tid & 63;
  int lr = lane & 15, lg = lane >> 4;
  int sx = (lane & 7) << 4;
  long row0 = (long)(blockIdx.x*4 + wid)*32;

  short8 af[2][2];
  #pragma unroll
  for (int m = 0; m < 2; ++m)
    #pragma unroll
    for (int s = 0; s < 2; ++s) {
      const float* xp = x + (row0 + m*16 + lr)*XX + s*32 + lg*8;
      float4 u0 = *(const float4*)xp;
      float4 u1 = *(const float4*)(xp + 4);
      short8 t;
      t[0]=f2bf(u0.x); t[1]=f2bf(u0.y); t[2]=f2bf(u0.z); t[3]=f2bf(u0.w);
      t[4]=f2bf(u1.x); t[5]=f2bf(u1.y); t[6]=f2bf(u1.z); t[7]=f2bf(u1.w);
      af[m][s] = t;
    }
  __syncthreads();

  const char* wbase = (const char*)wlds;
  f32x4 acc[2][8];
  #pragma unroll
  for (int m = 0; m < 2; ++m)
    #pragma unroll
    for (int np = 0; np < 8; ++np) acc[m][np] = (f32x4){0.f,0.f,0.f,0.f};

  #pragma unroll
  for (int np = 0; np < 8; ++np) {
    int col = np*16 + lr;
    #pragma unroll
    for (int s = 0; s < 2; ++s) {
      short8 bh = *(const short8*)(wbase + ((col*128 + s*64 + lg*16) ^ sx));
      #pragma unroll
      for (int m = 0; m < 2; ++m)
        acc[m][np] = __builtin_amdgcn_mfma_f32_16x16x32_bf16(af[m][s], bh, acc[m][np], 0, 0, 0);
    }
  }

  float gamv[8], betv[8], biasv[8];
  #pragma unroll
  for (int np = 0; np < 8; ++np) {
    int col = np*16 + lr;
    gamv[np] = g[col]; betv[np] = be[col]; biasv[np] = eb[col];
  }

  #pragma unroll
  for (int m = 0; m < 2; ++m) {
    float s4[4], q4[4];
    #pragma unroll
    for (int r = 0; r < 4; ++r) { s4[r] = 0.f; q4[r] = 0.f; }
    #pragma unroll
    for (int np = 0; np < 8; ++np)
      #pragma unroll
      for (int r = 0; r < 4; ++r) {
        float v = acc[m][np][r] + biasv[np];
        v = v > 0.f ? v : 0.01f*v;
        acc[m][np][r] = v;
        s4[r] += v; q4[r] += v*v;
      }
    #pragma unroll
    for (int off = 1; off < 16; off <<= 1)
      #pragma unroll
      for (int r = 0; r < 4; ++r) {
        s4[r] += __shfl_xor(s4[r], off);
        q4[r] += __shfl_xor(q4[r], off);
      }
    #pragma unroll
    for (int r = 0; r < 4; ++r) {
      float mu = s4[r] * (1.f/128.f);
      float var = q4[r] * (1.f/128.f) - mu*mu;
      float rs = rsqrtf(var + 1e-5f);
      long row = row0 + m*16 + lg*4 + r;
      #pragma unroll
      for (int np = 0; np < 8; ++np)
        hout[row*HH + np*16 + lr] = f2bf((acc[m][np][r]-mu)*rs*gamv[np] + betv[np]);
    }
  }
}

// K2: MFMA minGRU matmul [round-11 green numerics]. Now 512 threads = 8 waves,
// 8 chunks/block sharing one 64KB weight stage: 2 blocks/CU -> 16 waves/CU
// (2x round-11 occupancy at the same LDS footprint), staging traffic halved.
// Per-chunk computation/stores bit-identical to round 11.
__global__ __launch_bounds__(512) void gru_mm_kernel(
    const unsigned short* __restrict__ h, const unsigned short* __restrict__ wt,
    const float* __restrict__ bias,
    unsigned* __restrict__ ab, float* __restrict__ AsT, float* __restrict__ BsT)
{
  __shared__ short8 wlds[4096];   // 64 KB
  int tid = threadIdx.x;
  int wid = tid >> 6, lane = tid & 63;
  int chunk = blockIdx.x*8 + wid;
  int b = chunk >> 8, c = chunk & 255;
  long row0 = (long)b*TT + (long)c*CHUNK;
  int lr = lane & 15, lg = lane >> 4;
  int sx = (lane & 7) << 4;

  short8 af[2][4];
  #pragma unroll
  for (int m = 0; m < 2; ++m)
    #pragma unroll
    for (int s = 0; s < 4; ++s)
      af[m][s] = *(const short8*)(h + (row0 + m*16 + lr)*HH + s*32 + lg*8);

  const short8* wsrc = (const short8*)wt;
  #pragma unroll
  for (int i = 0; i < 8; ++i) wlds[i*512 + tid] = wsrc[i*512 + tid];
  __syncthreads();

  const char* wbase = (const char*)wlds;
  #pragma unroll 2
  for (int np = 0; np < 8; ++np) {
    f32x4 acch[2], accg[2];
    #pragma unroll
    for (int m = 0; m < 2; ++m) { acch[m] = (f32x4){0.f,0.f,0.f,0.f}; accg[m] = (f32x4){0.f,0.f,0.f,0.f}; }
    int rh = np*16 + lr;
    int rg = rh + 128;
    #pragma unroll
    for (int s = 0; s < 4; ++s) {
      short8 bh = *(const short8*)(wbase + ((rh*256 + s*64 + lg*16) ^ sx));
      short8 bg = *(const short8*)(wbase + ((rg*256 + s*64 + lg*16) ^ sx));
      #pragma unroll
      for (int m = 0; m < 2; ++m) {
        acch[m] = __builtin_amdgcn_mfma_f32_16x16x32_bf16(af[m][s], bh, acch[m], 0, 0, 0);
        accg[m] = __builtin_amdgcn_mfma_f32_16x16x32_bf16(af[m][s], bg, accg[m], 0, 0, 0);
      }
    }
    int col = np*16 + lr;
    float bh0 = bias[col], bg0 = bias[HH + col];
    float At[2], Bt[2];
    #pragma unroll
    for (int m = 0; m < 2; ++m) {
      float A4 = 1.f, B4 = 0.f;
      #pragma unroll
      for (int r = 0; r < 4; ++r) {
        float hid = acch[m][r] + bh0;
        float z = sigm(accg[m][r] + bg0);
        float gv = hid >= 0.f ? hid + 0.5f : sigm(hid);
        float av = 1.f - z, bv = z*gv;
        size_t grow = (size_t)(row0 + m*16 + lg*4 + r);
        ab[grow*HH + col] = (unsigned)f2bf(av) | ((unsigned)f2bf(bv) << 16);
        A4 *= av; B4 = av*B4 + bv;
      }
      #pragma unroll
      for (int off = 1; off < 4; off <<= 1) {
        float pa = __shfl_up(A4, off*16);
        float pb = __shfl_up(B4, off*16);
        float na = pa*A4, nb = A4*pb + B4;
        if (lg >= off) { A4 = na; B4 = nb; }
      }
      At[m] = __shfl(A4, 48 + lr);
      Bt[m] = __shfl(B4, 48 + lr);
    }
    if (lane < 16) {
      float Ac = At[0]*At[1];
      float Bc = At[1]*Bt[0] + Bt[1];
      size_t sidx = ((size_t)b*128 + col)*256 + c;   // transposed
      AsT[sidx] = Ac;
      BsT[sidx] = Bc;
    }
  }
}

// K3: wave-parallel scan — 1024 waves, one (b,d) row each; Kogge-Stone over 256
// chunk summaries with coalesced float4 loads. [round-5 green text]
__global__ __launch_bounds__(256) void scan2_kernel(
    const float* __restrict__ AsT, const float* __restrict__ BsT, float* __restrict__ carT)
{
  int wid = threadIdx.x >> 6, lane = threadIdx.x & 63;
  int s = blockIdx.x*4 + wid;     // 0..1023 = b*128+d
  float4 Av = ((const float4*)(AsT + (size_t)s*256))[lane];
  float4 Bv = ((const float4*)(BsT + (size_t)s*256))[lane];
  float Ai = Av.x, Bi = Bv.x;
  Bi = Av.y*Bi + Bv.y; Ai = Av.y*Ai;
  Bi = Av.z*Bi + Bv.z; Ai = Av.z*Ai;
  Bi = Av.w*Bi + Bv.w; Ai = Av.w*Ai;
  #pragma unroll
  for (int off = 1; off < 64; off <<= 1) {
    float pA = __shfl_up(Ai, off);
    float pB = __shfl_up(Bi, off);
    if (lane >= off) { Bi = Ai*pB + Bi; Ai = Ai*pA; }
  }
  float exB = __shfl_up(Bi, 1);
  if (lane == 0) exB = 0.f;
  float run = exB;
  float4 cv;
  cv.x = run; run = Av.x*run + Bv.x;
  cv.y = run; run = Av.y*run + Bv.y;
  cv.z = run; run = Av.z*run + Bv.z;
  cv.w = run;
  ((float4*)(carT + (size_t)s*256))[lane] = cv;
}

// K4: apply recurrence + fused LN -> h (bf16). [round-5 green text]
__global__ __launch_bounds__(256) void apply_kernel(
    const unsigned* __restrict__ ab, const float* __restrict__ carT,
    const float* __restrict__ g, const float* __restrict__ be,
    unsigned short* __restrict__ hout)
{
  int tid = threadIdx.x, wid = tid >> 6, lane = tid & 63;
  int chunk = blockIdx.x*4 + wid;
  int b = chunk >> 8, c = chunk & 255;
  float2 hc;
  hc.x = carT[((size_t)b*128 + 2*lane    )*256 + c];
  hc.y = carT[((size_t)b*128 + 2*lane + 1)*256 + c];
  float2 gam = ((const float2*)g)[lane];
  float2 bet = ((const float2*)be)[lane];
  size_t rowbase = (size_t)chunk*CHUNK;
  for (int gq = 0; gq < 4; ++gq) {
    uint2 v[8];
    #pragma unroll
    for (int j = 0; j < 8; ++j)
      v[j] = ((const uint2*)(ab + (rowbase + gq*8 + j)*HH))[lane];
    #pragma unroll
    for (int j = 0; j < 8; ++j) {
      float ax = bf2f(v[j].x & 0xffffu), bx = bf2f(v[j].x >> 16);
      float ay = bf2f(v[j].y & 0xffffu), by = bf2f(v[j].y >> 16);
      hc.x = ax*hc.x + bx;
      hc.y = ay*hc.y + by;
      float s = hc.x + hc.y, q = hc.x*hc.x + hc.y*hc.y;
      #pragma unroll
      for (int m = 1; m < 64; m <<= 1) { s += __shfl_xor(s, m); q += __shfl_xor(q, m); }
      float mu = s * (1.f/128.f);
      float var = q * (1.f/128.f) - mu*mu;
      float rs = rsqrtf(var + 1e-5f);
      unsigned o = (unsigned)f2bf((hc.x-mu)*rs*gam.x + bet.x)
                 | ((unsigned)f2bf((hc.y-mu)*rs*gam.y + bet.y) << 16);
      ((unsigned*)hout)[(rowbase + gq*8 + j)*64 + lane] = o;
    }
  }
}

// K5: proj (128->50 padded to 64) MFMA + softplus [round-5 green text]
__global__ __launch_bounds__(256) void proj_mfma_kernel(
    const unsigned short* __restrict__ hin, const unsigned short* __restrict__ wt_p,
    const float* __restrict__ pb, float* __restrict__ out)
{
  __shared__ short8 wlds[1024];
  int tid = threadIdx.x;
  const short8* wsrc = (const short8*)wt_p;
  #pragma unroll
  for (int i = 0; i < 4; ++i) wlds[i*256 + tid] = wsrc[i*256 + tid];

  int wid = tid >> 6, lane = tid & 63;
  int lr = lane & 15, lg = lane >> 4;
  int sx = (lane & 7) << 4;
  long row0 = (long)(blockIdx.x*4 + wid)*32;

  short8 af[2][4];
  #pragma unroll
  for (int m = 0; m < 2; ++m)
    #pragma unroll
    for (int s = 0; s < 4; ++s)
      af[m][s] = *(const short8*)(hin + (row0 + m*16 + lr)*HH + s*32 + lg*8);
  __syncthreads();

  const char* wbase = (const char*)wlds;
  f32x4 acc[2][4];
  #pragma unroll
  for (int m = 0; m < 2; ++m)
    #pragma unroll
    for (int np = 0; np < 4; ++np) acc[m][np] = (f32x4){0.f,0.f,0.f,0.f};

  #pragma unroll
  for (int np = 0; np < 4; ++np) {
    int col = np*16 + lr;
    #pragma unroll
    for (int s = 0; s < 4; ++s) {
      short8 bh = *(const short8*)(wbase + ((col*256 + s*64 + lg*16) ^ sx));
      #pragma unroll
      for (int m = 0; m < 2; ++m)
        acc[m][np] = __builtin_amdgcn_mfma_f32_16x16x32_bf16(af[m][s], bh, acc[m][np], 0, 0, 0);
    }
  }

  #pragma unroll
  for (int np = 0; np < 4; ++np) {
    int col = np*16 + lr;
    bool act = col < 50;
    float bias = act ? pb[col] : 0.f;
    #pragma unroll
    for (int m = 0; m < 2; ++m)
      #pragma unroll
      for (int r = 0; r < 4; ++r) {
        float v = acc[m][np][r] + bias;
        float sp = fmaxf(v, 0.f) + log1pf(__expf(-fabsf(v)));
        if (act) out[(row0 + m*16 + lg*4 + r)*50 + col] = sp;
      }
  }
}

extern "C" void kernel_launch(void* const* d_in, const int* in_sizes, int n_in,
                              void* d_out, int out_size, void* d_ws, size_t ws_size,
                              hipStream_t stream) {
  const float* x    = (const float*)d_in[0];
  const float* ew   = (const float*)d_in[1];
  const float* eb   = (const float*)d_in[2];
  const float* ln0g = (const float*)d_in[3];
  const float* ln0b = (const float*)d_in[4];
  const float* pw   = (const float*)d_in[5];
  const float* pb   = (const float*)d_in[6];
  float* out = (float*)d_out;

  size_t nBT  = (size_t)BB*TT*HH;
  size_t nSum = (size_t)BB*NC*HH;
  unsigned short* h  = (unsigned short*)d_ws;
  unsigned*       ab = (unsigned*)(h + nBT);
  float* AsT  = (float*)(ab + nBT);
  float* BsT  = AsT + nSum;
  float* carT = BsT + nSum;
  unsigned short* wt   = (unsigned short*)(carT + nSum);
  unsigned short* wt_e = wt + 3*32768;
  unsigned short* wt_p = wt_e + 8192;

  prep_kernel<<<448, 256, 0, stream>>>((const float*)d_in[7], (const float*)d_in[11],
                                       (const float*)d_in[15], ew, pw, wt, wt_e, wt_p);
  embed_mfma_kernel<<<(BB*TT)/128, 256, 0, stream>>>(x, wt_e, eb, ln0g, ln0b, h);

  for (int l = 0; l < 3; ++l) {
    const float* gb = (const float*)d_in[8 + 4*l];
    const float* lg = (const float*)d_in[9 + 4*l];
    const float* lb = (const float*)d_in[10 + 4*l];
    gru_mm_kernel<<<(BB*NC)/8, 512, 0, stream>>>(h, wt + (size_t)l*32768, gb, ab, AsT, BsT);
    scan2_kernel<<<256, 256, 0, stream>>>(AsT, BsT, carT);
    apply_kernel<<<(BB*NC)/4, 256, 0, stream>>>(ab, carT, lg, lb, h);
  }

  proj_mfma_kernel<<<(BB*TT)/128, 256, 0, stream>>>(h, wt_p, pb, out);
}

// Round 13
// 141.891 us; speedup vs baseline: 1.0514x; 1.0514x over previous
//
#include <hip/hip_runtime.h>
#include <math.h>

#define BB 8
#define TT 8192
#define XX 64
#define HH 128
#define CHUNK 32
#define NC (TT/CHUNK)

typedef __attribute__((ext_vector_type(8))) short short8;
typedef __attribute__((ext_vector_type(4))) float f32x4;

// fast sigmoid: v_rcp_f32 (~1 ulp) instead of IEEE div sequence. Used only in
// gru_mm, where ab/summaries/replay all consume the same values -> consistent.
__device__ __forceinline__ float sigm(float x){
  return __builtin_amdgcn_rcpf(1.0f + __expf(-x));
}
__device__ __forceinline__ unsigned short f2bf(float f){
  unsigned u = __float_as_uint(f);
  return (unsigned short)((u + 0x7fffu + ((u>>16)&1u)) >> 16);
}
__device__ __forceinline__ float bf2f(unsigned b){ return __uint_as_float(b << 16); }

// P0: build bf16 weight tables, pre-swizzled (byte ^= (col&7)<<4) so MFMA kernels
// stage LDS linearly and read with the same XOR -> conflict-free ds_read_b128.
__global__ __launch_bounds__(256) void prep_kernel(
    const float* __restrict__ w1, const float* __restrict__ w2, const float* __restrict__ w3,
    const float* __restrict__ ew, const float* __restrict__ pw,
    unsigned short* __restrict__ wt, unsigned short* __restrict__ wt_e, unsigned short* __restrict__ wt_p)
{
  int idx = blockIdx.x*256 + threadIdx.x;
  if (idx < 98304) {
    int l = idx >> 15;
    int e = idx & 32767;
    int k = e >> 8;
    int col = e & 255;
    const float* w = (l==0) ? w1 : ((l==1) ? w2 : w3);
    float v = w[e];
    unsigned byte = ((unsigned)col*128u + (unsigned)k)*2u;
    byte ^= (unsigned)((col & 7) << 4);
    wt[(size_t)l*32768 + (byte >> 1)] = f2bf(v);
  } else if (idx < 106496) {
    int e = idx - 98304;
    int col = e >> 6, k = e & 63;
    float v = ew[k*HH + col];
    unsigned byte = ((unsigned)e*2u) ^ (unsigned)((col & 7) << 4);
    wt_e[byte >> 1] = f2bf(v);
  } else if (idx < 114688) {
    int e = idx - 106496;
    int col = e >> 7, k = e & 127;
    float v = (col < 50) ? pw[k*50 + col] : 0.f;
    unsigned byte = ((unsigned)e*2u) ^ (unsigned)((col & 7) << 4);
    wt_p[byte >> 1] = f2bf(v);
  }
}

// K1: embed (64->128) MFMA + leaky_relu + LN0 -> h (bf16)   [round-5 green text]
__global__ __launch_bounds__(256) void embed_mfma_kernel(
    const float* __restrict__ x, const unsigned short* __restrict__ wt_e,
    const float* __restrict__ eb, const float* __restrict__ g, const float* __restrict__ be,
    unsigned short* __restrict__ hout)
{
  __shared__ short8 wlds[1024];
  int tid = threadIdx.x;
  const short8* wsrc = (const short8*)wt_e;
  #pragma unroll
  for (int i = 0; i < 4; ++i) wlds[i*256 + tid] = wsrc[i*256 + tid];

  int wid = tid >> 6, lane = tid & 63;
  int lr = lane & 15, lg = lane >> 4;
  int sx = (lane & 7) << 4;
  long row0 = (long)(blockIdx.x*4 + wid)*32;

  short8 af[2][2];
  #pragma unroll
  for (int m = 0; m < 2; ++m)
    #pragma unroll
    for (int s = 0; s < 2; ++s) {
      const float* xp = x + (row0 + m*16 + lr)*XX + s*32 + lg*8;
      float4 u0 = *(const float4*)xp;
      float4 u1 = *(const float4*)(xp + 4);
      short8 t;
      t[0]=f2bf(u0.x); t[1]=f2bf(u0.y); t[2]=f2bf(u0.z); t[3]=f2bf(u0.w);
      t[4]=f2bf(u1.x); t[5]=f2bf(u1.y); t[6]=f2bf(u1.z); t[7]=f2bf(u1.w);
      af[m][s] = t;
    }
  __syncthreads();

  const char* wbase = (const char*)wlds;
  f32x4 acc[2][8];
  #pragma unroll
  for (int m = 0; m < 2; ++m)
    #pragma unroll
    for (int np = 0; np < 8; ++np) acc[m][np] = (f32x4){0.f,0.f,0.f,0.f};

  #pragma unroll
  for (int np = 0; np < 8; ++np) {
    int col = np*16 + lr;
    #pragma unroll
    for (int s = 0; s < 2; ++s) {
      short8 bh = *(const short8*)(wbase + ((col*128 + s*64 + lg*16) ^ sx));
      #pragma unroll
      for (int m = 0; m < 2; ++m)
        acc[m][np] = __builtin_amdgcn_mfma_f32_16x16x32_bf16(af[m][s], bh, acc[m][np], 0, 0, 0);
    }
  }

  float gamv[8], betv[8], biasv[8];
  #pragma unroll
  for (int np = 0; np < 8; ++np) {
    int col = np*16 + lr;
    gamv[np] = g[col]; betv[np] = be[col]; biasv[np] = eb[col];
  }

  #pragma unroll
  for (int m = 0; m < 2; ++m) {
    float s4[4], q4[4];
    #pragma unroll
    for (int r = 0; r < 4; ++r) { s4[r] = 0.f; q4[r] = 0.f; }
    #pragma unroll
    for (int np = 0; np < 8; ++np)
      #pragma unroll
      for (int r = 0; r < 4; ++r) {
        float v = acc[m][np][r] + biasv[np];
        v = v > 0.f ? v : 0.01f*v;
        acc[m][np][r] = v;
        s4[r] += v; q4[r] += v*v;
      }
    #pragma unroll
    for (int off = 1; off < 16; off <<= 1)
      #pragma unroll
      for (int r = 0; r < 4; ++r) {
        s4[r] += __shfl_xor(s4[r], off);
        q4[r] += __shfl_xor(q4[r], off);
      }
    #pragma unroll
    for (int r = 0; r < 4; ++r) {
      float mu = s4[r] * (1.f/128.f);
      float var = q4[r] * (1.f/128.f) - mu*mu;
      float rs = rsqrtf(var + 1e-5f);
      long row = row0 + m*16 + lg*4 + r;
      #pragma unroll
      for (int np = 0; np < 8; ++np)
        hout[row*HH + np*16 + lr] = f2bf((acc[m][np][r]-mu)*rs*gamv[np] + betv[np]);
    }
  }
}

// K2: MFMA minGRU matmul [round-11 green text: 256 threads, 4 waves, 64KB LDS]
__global__ __launch_bounds__(256) void gru_mm_kernel(
    const unsigned short* __restrict__ h, const unsigned short* __restrict__ wt,
    const float* __restrict__ bias,
    unsigned* __restrict__ ab, float* __restrict__ AsT, float* __restrict__ BsT)
{
  __shared__ short8 wlds[4096];   // 64 KB
  int tid = threadIdx.x;
  int wid = tid >> 6, lane = tid & 63;
  int chunk = blockIdx.x*4 + wid;
  int b = chunk >> 8, c = chunk & 255;
  long row0 = (long)b*TT + (long)c*CHUNK;
  int lr = lane & 15, lg = lane >> 4;
  int sx = (lane & 7) << 4;

  short8 af[2][4];
  #pragma unroll
  for (int m = 0; m < 2; ++m)
    #pragma unroll
    for (int s = 0; s < 4; ++s)
      af[m][s] = *(const short8*)(h + (row0 + m*16 + lr)*HH + s*32 + lg*8);

  const short8* wsrc = (const short8*)wt;
  #pragma unroll
  for (int i = 0; i < 16; ++i) wlds[i*256 + tid] = wsrc[i*256 + tid];
  __syncthreads();

  const char* wbase = (const char*)wlds;
  #pragma unroll 2
  for (int np = 0; np < 8; ++np) {
    f32x4 acch[2], accg[2];
    #pragma unroll
    for (int m = 0; m < 2; ++m) { acch[m] = (f32x4){0.f,0.f,0.f,0.f}; accg[m] = (f32x4){0.f,0.f,0.f,0.f}; }
    int rh = np*16 + lr;
    int rg = rh + 128;
    #pragma unroll
    for (int s = 0; s < 4; ++s) {
      short8 bh = *(const short8*)(wbase + ((rh*256 + s*64 + lg*16) ^ sx));
      short8 bg = *(const short8*)(wbase + ((rg*256 + s*64 + lg*16) ^ sx));
      #pragma unroll
      for (int m = 0; m < 2; ++m) {
        acch[m] = __builtin_amdgcn_mfma_f32_16x16x32_bf16(af[m][s], bh, acch[m], 0, 0, 0);
        accg[m] = __builtin_amdgcn_mfma_f32_16x16x32_bf16(af[m][s], bg, accg[m], 0, 0, 0);
      }
    }
    int col = np*16 + lr;
    float bh0 = bias[col], bg0 = bias[HH + col];
    float At[2], Bt[2];
    #pragma unroll
    for (int m = 0; m < 2; ++m) {
      float A4 = 1.f, B4 = 0.f;
      #pragma unroll
      for (int r = 0; r < 4; ++r) {
        float hid = acch[m][r] + bh0;
        float z = sigm(accg[m][r] + bg0);
        float gv = hid >= 0.f ? hid + 0.5f : sigm(hid);
        float av = 1.f - z, bv = z*gv;
        size_t grow = (size_t)(row0 + m*16 + lg*4 + r);
        ab[grow*HH + col] = (unsigned)f2bf(av) | ((unsigned)f2bf(bv) << 16);
        A4 *= av; B4 = av*B4 + bv;
      }
      #pragma unroll
      for (int off = 1; off < 4; off <<= 1) {
        float pa = __shfl_up(A4, off*16);
        float pb = __shfl_up(B4, off*16);
        float na = pa*A4, nb = A4*pb + B4;
        if (lg >= off) { A4 = na; B4 = nb; }
      }
      At[m] = __shfl(A4, 48 + lr);
      Bt[m] = __shfl(B4, 48 + lr);
    }
    if (lane < 16) {
      float Ac = At[0]*At[1];
      float Bc = At[1]*Bt[0] + Bt[1];
      size_t sidx = ((size_t)b*128 + col)*256 + c;   // transposed
      AsT[sidx] = Ac;
      BsT[sidx] = Bc;
    }
  }
}

// K3: wave-parallel scan [round-5 green text]
__global__ __launch_bounds__(256) void scan2_kernel(
    const float* __restrict__ AsT, const float* __restrict__ BsT, float* __restrict__ carT)
{
  int wid = threadIdx.x >> 6, lane = threadIdx.x & 63;
  int s = blockIdx.x*4 + wid;     // 0..1023 = b*128+d
  float4 Av = ((const float4*)(AsT + (size_t)s*256))[lane];
  float4 Bv = ((const float4*)(BsT + (size_t)s*256))[lane];
  float Ai = Av.x, Bi = Bv.x;
  Bi = Av.y*Bi + Bv.y; Ai = Av.y*Ai;
  Bi = Av.z*Bi + Bv.z; Ai = Av.z*Ai;
  Bi = Av.w*Bi + Bv.w; Ai = Av.w*Ai;
  #pragma unroll
  for (int off = 1; off < 64; off <<= 1) {
    float pA = __shfl_up(Ai, off);
    float pB = __shfl_up(Bi, off);
    if (lane >= off) { Bi = Ai*pB + Bi; Ai = Ai*pA; }
  }
  float exB = __shfl_up(Bi, 1);
  if (lane == 0) exB = 0.f;
  float run = exB;
  float4 cv;
  cv.x = run; run = Av.x*run + Bv.x;
  cv.y = run; run = Av.y*run + Bv.y;
  cv.z = run; run = Av.z*run + Bv.z;
  cv.w = run;
  ((float4*)(carT + (size_t)s*256))[lane] = cv;
}

// K4: apply recurrence + fused LN -> h (bf16). [round-5 green text, layers 1-2]
__global__ __launch_bounds__(256) void apply_kernel(
    const unsigned* __restrict__ ab, const float* __restrict__ carT,
    const float* __restrict__ g, const float* __restrict__ be,
    unsigned short* __restrict__ hout)
{
  int tid = threadIdx.x, wid = tid >> 6, lane = tid & 63;
  int chunk = blockIdx.x*4 + wid;
  int b = chunk >> 8, c = chunk & 255;
  float2 hc;
  hc.x = carT[((size_t)b*128 + 2*lane    )*256 + c];
  hc.y = carT[((size_t)b*128 + 2*lane + 1)*256 + c];
  float2 gam = ((const float2*)g)[lane];
  float2 bet = ((const float2*)be)[lane];
  size_t rowbase = (size_t)chunk*CHUNK;
  for (int gq = 0; gq < 4; ++gq) {
    uint2 v[8];
    #pragma unroll
    for (int j = 0; j < 8; ++j)
      v[j] = ((const uint2*)(ab + (rowbase + gq*8 + j)*HH))[lane];
    #pragma unroll
    for (int j = 0; j < 8; ++j) {
      float ax = bf2f(v[j].x & 0xffffu), bx = bf2f(v[j].x >> 16);
      float ay = bf2f(v[j].y & 0xffffu), by = bf2f(v[j].y >> 16);
      hc.x = ax*hc.x + bx;
      hc.y = ay*hc.y + by;
      float s = hc.x + hc.y, q = hc.x*hc.x + hc.y*hc.y;
      #pragma unroll
      for (int m = 1; m < 64; m <<= 1) { s += __shfl_xor(s, m); q += __shfl_xor(q, m); }
      float mu = s * (1.f/128.f);
      float var = q * (1.f/128.f) - mu*mu;
      float rs = rsqrtf(var + 1e-5f);
      unsigned o = (unsigned)f2bf((hc.x-mu)*rs*gam.x + bet.x)
                 | ((unsigned)f2bf((hc.y-mu)*rs*gam.y + bet.y) << 16);
      ((unsigned*)hout)[(rowbase + gq*8 + j)*64 + lane] = o;
    }
  }
}

// K4b (layer 3 only): apply + LN -> per-wave LDS h-tile (XOR-swizzled) -> proj MFMA
// + softplus -> out. Same bf16 bits as apply->proj through HBM, so bit-identical
// output; saves the 33.6 MB h round-trip and the separate proj dispatch.
// LDS: wt_p 16KB + 4 waves x 8KB h-tile = 48KB.
__global__ __launch_bounds__(256) void apply_proj_kernel(
    const unsigned* __restrict__ ab, const float* __restrict__ carT,
    const float* __restrict__ g, const float* __restrict__ be,
    const unsigned short* __restrict__ wt_p, const float* __restrict__ pb,
    float* __restrict__ out)
{
  __shared__ short8 wlds[1024];        // 16 KB proj weights
  __shared__ unsigned hlds[4*2048];    // 32 KB: per-wave 32x128 bf16 tile (as 32x64 uints)
  int tid = threadIdx.x, wid = tid >> 6, lane = tid & 63;
  const short8* wsrc = (const short8*)wt_p;
  #pragma unroll
  for (int i = 0; i < 4; ++i) wlds[i*256 + tid] = wsrc[i*256 + tid];

  int chunk = blockIdx.x*4 + wid;
  int b = chunk >> 8, c = chunk & 255;
  float2 hc;
  hc.x = carT[((size_t)b*128 + 2*lane    )*256 + c];
  hc.y = carT[((size_t)b*128 + 2*lane + 1)*256 + c];
  float2 gam = ((const float2*)g)[lane];
  float2 bet = ((const float2*)be)[lane];
  size_t rowbase = (size_t)chunk*CHUNK;
  unsigned* myh = hlds + wid*2048;

  // ---- apply phase (round-5 text, destination = LDS tile) ----
  for (int gq = 0; gq < 4; ++gq) {
    uint2 v[8];
    #pragma unroll
    for (int j = 0; j < 8; ++j)
      v[j] = ((const uint2*)(ab + (rowbase + gq*8 + j)*HH))[lane];
    #pragma unroll
    for (int j = 0; j < 8; ++j) {
      float ax = bf2f(v[j].x & 0xffffu), bx = bf2f(v[j].x >> 16);
      float ay = bf2f(v[j].y & 0xffffu), by = bf2f(v[j].y >> 16);
      hc.x = ax*hc.x + bx;
      hc.y = ay*hc.y + by;
      float s = hc.x + hc.y, q = hc.x*hc.x + hc.y*hc.y;
      #pragma unroll
      for (int m2 = 1; m2 < 64; m2 <<= 1) { s += __shfl_xor(s, m2); q += __shfl_xor(q, m2); }
      float mu = s * (1.f/128.f);
      float var = q * (1.f/128.f) - mu*mu;
      float rs = rsqrtf(var + 1e-5f);
      unsigned o = (unsigned)f2bf((hc.x-mu)*rs*gam.x + bet.x)
                 | ((unsigned)f2bf((hc.y-mu)*rs*gam.y + bet.y) << 16);
      int t = gq*8 + j;
      myh[(t*64 + lane) ^ ((t & 7) << 2)] = o;   // XOR-swizzled h tile
    }
  }
  __syncthreads();   // wt_p staged + all h tiles written

  // ---- proj phase (proj_mfma text; A from LDS tile, same swizzle) ----
  int lr = lane & 15, lg = lane >> 4;
  int sx = (lane & 7) << 4;
  short8 af[2][4];
  #pragma unroll
  for (int m = 0; m < 2; ++m)
    #pragma unroll
    for (int s = 0; s < 4; ++s) {
      int row = m*16 + lr;
      af[m][s] = *(const short8*)(myh + (((row*64) + s*16 + lg*4) ^ ((row & 7) << 2)));
    }

  const char* wbase = (const char*)wlds;
  f32x4 acc[2][4];
  #pragma unroll
  for (int m = 0; m < 2; ++m)
    #pragma unroll
    for (int np = 0; np < 4; ++np) acc[m][np] = (f32x4){0.f,0.f,0.f,0.f};

  #pragma unroll
  for (int np = 0; np < 4; ++np) {
    int col = np*16 + lr;
    #pragma unroll
    for (int s = 0; s < 4; ++s) {
      short8 bh = *(const short8*)(wbase + ((col*256 + s*64 + lg*16) ^ sx));
      #pragma unroll
      for (int m = 0; m < 2; ++m)
        acc[m][np] = __builtin_amdgcn_mfma_f32_16x16x32_bf16(af[m][s], bh, acc[m][np], 0, 0, 0);
    }
  }

  #pragma unroll
  for (int np = 0; np < 4; ++np) {
    int col = np*16 + lr;
    bool act = col < 50;
    float bias = act ? pb[col] : 0.f;
    #pragma unroll
    for (int m = 0; m < 2; ++m)
      #pragma unroll
      for (int r = 0; r < 4; ++r) {
        float v = acc[m][np][r] + bias;
        float sp = fmaxf(v, 0.f) + log1pf(__expf(-fabsf(v)));
        if (act) out[(rowbase + m*16 + lg*4 + r)*50 + col] = sp;
      }
  }
}

extern "C" void kernel_launch(void* const* d_in, const int* in_sizes, int n_in,
                              void* d_out, int out_size, void* d_ws, size_t ws_size,
                              hipStream_t stream) {
  const float* x    = (const float*)d_in[0];
  const float* ew   = (const float*)d_in[1];
  const float* eb   = (const float*)d_in[2];
  const float* ln0g = (const float*)d_in[3];
  const float* ln0b = (const float*)d_in[4];
  const float* pw   = (const float*)d_in[5];
  const float* pb   = (const float*)d_in[6];
  float* out = (float*)d_out;

  size_t nBT  = (size_t)BB*TT*HH;
  size_t nSum = (size_t)BB*NC*HH;
  unsigned short* h  = (unsigned short*)d_ws;
  unsigned*       ab = (unsigned*)(h + nBT);
  float* AsT  = (float*)(ab + nBT);
  float* BsT  = AsT + nSum;
  float* carT = BsT + nSum;
  unsigned short* wt   = (unsigned short*)(carT + nSum);
  unsigned short* wt_e = wt + 3*32768;
  unsigned short* wt_p = wt_e + 8192;

  prep_kernel<<<448, 256, 0, stream>>>((const float*)d_in[7], (const float*)d_in[11],
                                       (const float*)d_in[15], ew, pw, wt, wt_e, wt_p);
  embed_mfma_kernel<<<(BB*TT)/128, 256, 0, stream>>>(x, wt_e, eb, ln0g, ln0b, h);

  for (int l = 0; l < 3; ++l) {
    const float* gb = (const float*)d_in[8 + 4*l];
    const float* lg = (const float*)d_in[9 + 4*l];
    const float* lb = (const float*)d_in[10 + 4*l];
    gru_mm_kernel<<<(BB*NC)/4, 256, 0, stream>>>(h, wt + (size_t)l*32768, gb, ab, AsT, BsT);
    scan2_kernel<<<256, 256, 0, stream>>>(AsT, BsT, carT);
    if (l < 2) {
      apply_kernel<<<(BB*NC)/4, 256, 0, stream>>>(ab, carT, lg, lb, h);
    } else {
      apply_proj_kernel<<<(BB*NC)/4, 256, 0, stream>>>(ab, carT, lg, lb, wt_p, pb, out);
    }
  }
}